// Round 1
// baseline (1016.041 us; speedup 1.0000x reference)
//
#include <hip/hip_runtime.h>

// segment_sum: out[col_idx[i]] += values[i], out has n_cols elements.
// Inputs (setup_inputs order): d_in[0]=row_idx (UNUSED), d_in[1]=col_idx (int32),
// d_in[2]=values (f32), d_in[3]=n_rows (scalar), d_in[4]=n_cols (scalar).
// Output: float32[n_cols].

__global__ void zero_out_kernel(float* __restrict__ out, int n) {
    int i = blockIdx.x * blockDim.x + threadIdx.x;
    if (i < n) out[i] = 0.0f;
}

__global__ void scatter_add_kernel(const int* __restrict__ col_idx,
                                   const float* __restrict__ values,
                                   float* __restrict__ out,
                                   int nnz) {
    const int tid    = blockIdx.x * blockDim.x + threadIdx.x;
    const int stride = gridDim.x * blockDim.x;

    const int nvec = nnz >> 2;  // number of complete int4/float4 groups
    const int4*   c4 = reinterpret_cast<const int4*>(col_idx);
    const float4* v4 = reinterpret_cast<const float4*>(values);

    for (int v = tid; v < nvec; v += stride) {
        int4   c = c4[v];
        float4 x = v4[v];
        atomicAdd(&out[c.x], x.x);
        atomicAdd(&out[c.y], x.y);
        atomicAdd(&out[c.z], x.z);
        atomicAdd(&out[c.w], x.w);
    }

    // tail (nnz not divisible by 4)
    for (int i = (nvec << 2) + tid; i < nnz; i += stride) {
        atomicAdd(&out[col_idx[i]], values[i]);
    }
}

extern "C" void kernel_launch(void* const* d_in, const int* in_sizes, int n_in,
                              void* d_out, int out_size, void* d_ws, size_t ws_size,
                              hipStream_t stream) {
    const int*   col_idx = (const int*)d_in[1];
    const float* values  = (const float*)d_in[2];
    float*       out     = (float*)d_out;
    const int    nnz     = in_sizes[2];

    // 1) zero the output (harness poisons d_out; we must produce exact sums)
    {
        const int threads = 256;
        const int blocks  = (out_size + threads - 1) / threads;
        zero_out_kernel<<<blocks, threads, 0, stream>>>(out, out_size);
    }

    // 2) vectorized grid-stride scatter-add
    {
        const int threads = 256;
        const int blocks  = 2048;  // ~8 blocks/CU worth of waves; grid-stride covers rest
        scatter_add_kernel<<<blocks, threads, 0, stream>>>(col_idx, values, out, nnz);
    }
}

// Round 2
// 1009.647 us; speedup vs baseline: 1.0063x; 1.0063x over previous
//
#include <hip/hip_runtime.h>

// segment_sum: out[col_idx[i]] += values[i], out has n_cols elements.
// Inputs: d_in[0]=row_idx (UNUSED), d_in[1]=col_idx (int32), d_in[2]=values (f32),
// d_in[3]=n_rows (scalar), d_in[4]=n_cols (scalar). Output: float32[n_cols].
//
// Strategy: per-workgroup private dense accumulators in d_ws, updated with
// WORKGROUP-scope atomics (execute in local XCD L2, no HBM write-through),
// then a tree-less reduce over the NB copies. Device-scope atomics (round 1)
// cost 32B HBM write-through per atomic -> 623 MB of writes, 1016 us.

#define NB   64     // number of private copies == number of scatter blocks
#define TPB  1024   // threads per scatter block

__device__ __forceinline__ void wg_atomic_add(float* p, float v) {
    // workgroup scope: only the owning workgroup ever touches this copy,
    // so L2-local atomic execution is correct (no cross-XCD coherence needed).
    __hip_atomic_fetch_add(p, v, __ATOMIC_RELAXED, __HIP_MEMORY_SCOPE_WORKGROUP);
}

__global__ void zero_ws_kernel(float4* __restrict__ ws, int nvec4) {
    int i = blockIdx.x * blockDim.x + threadIdx.x;
    int stride = gridDim.x * blockDim.x;
    float4 z = {0.f, 0.f, 0.f, 0.f};
    for (int v = i; v < nvec4; v += stride) ws[v] = z;
}

__global__ void zero_out_kernel(float* __restrict__ out, int n) {
    int i = blockIdx.x * blockDim.x + threadIdx.x;
    if (i < n) out[i] = 0.0f;
}

__global__ void scatter_priv_kernel(const int* __restrict__ col_idx,
                                    const float* __restrict__ values,
                                    float* __restrict__ ws,
                                    int nnz, int copy_stride) {
    float* priv = ws + (size_t)blockIdx.x * copy_stride;
    const int tid      = blockIdx.x * blockDim.x + threadIdx.x;
    const int nthreads = gridDim.x * blockDim.x;

    const int nvec = nnz >> 2;
    const int4*   c4 = reinterpret_cast<const int4*>(col_idx);
    const float4* v4 = reinterpret_cast<const float4*>(values);

    int v = tid;
    // 4x unrolled: 8 loads (128 B) in flight per thread before any atomic waits
    for (; v + 3 * nthreads < nvec; v += 4 * nthreads) {
        int4   c0 = c4[v];
        int4   c1 = c4[v + nthreads];
        int4   c2 = c4[v + 2 * nthreads];
        int4   c3 = c4[v + 3 * nthreads];
        float4 x0 = v4[v];
        float4 x1 = v4[v + nthreads];
        float4 x2 = v4[v + 2 * nthreads];
        float4 x3 = v4[v + 3 * nthreads];
        wg_atomic_add(&priv[c0.x], x0.x); wg_atomic_add(&priv[c0.y], x0.y);
        wg_atomic_add(&priv[c0.z], x0.z); wg_atomic_add(&priv[c0.w], x0.w);
        wg_atomic_add(&priv[c1.x], x1.x); wg_atomic_add(&priv[c1.y], x1.y);
        wg_atomic_add(&priv[c1.z], x1.z); wg_atomic_add(&priv[c1.w], x1.w);
        wg_atomic_add(&priv[c2.x], x2.x); wg_atomic_add(&priv[c2.y], x2.y);
        wg_atomic_add(&priv[c2.z], x2.z); wg_atomic_add(&priv[c2.w], x2.w);
        wg_atomic_add(&priv[c3.x], x3.x); wg_atomic_add(&priv[c3.y], x3.y);
        wg_atomic_add(&priv[c3.z], x3.z); wg_atomic_add(&priv[c3.w], x3.w);
    }
    for (; v < nvec; v += nthreads) {
        int4   c = c4[v];
        float4 x = v4[v];
        wg_atomic_add(&priv[c.x], x.x); wg_atomic_add(&priv[c.y], x.y);
        wg_atomic_add(&priv[c.z], x.z); wg_atomic_add(&priv[c.w], x.w);
    }
    for (int i = (nvec << 2) + tid; i < nnz; i += nthreads) {
        wg_atomic_add(&priv[col_idx[i]], values[i]);
    }
}

__global__ void reduce_priv_kernel(const float* __restrict__ ws,
                                   float* __restrict__ out,
                                   int ncols, int copy_stride) {
    int c = blockIdx.x * blockDim.x + threadIdx.x;
    if (c >= ncols) return;
    float s = 0.f;
#pragma unroll 8
    for (int b = 0; b < NB; ++b) s += ws[(size_t)b * copy_stride + c];
    out[c] = s;
}

// fallback: direct device-scope atomics (round-1 kernel) if ws too small
__global__ void scatter_add_kernel(const int* __restrict__ col_idx,
                                   const float* __restrict__ values,
                                   float* __restrict__ out, int nnz) {
    const int tid    = blockIdx.x * blockDim.x + threadIdx.x;
    const int stride = gridDim.x * blockDim.x;
    const int nvec = nnz >> 2;
    const int4*   c4 = reinterpret_cast<const int4*>(col_idx);
    const float4* v4 = reinterpret_cast<const float4*>(values);
    for (int v = tid; v < nvec; v += stride) {
        int4 c = c4[v]; float4 x = v4[v];
        atomicAdd(&out[c.x], x.x); atomicAdd(&out[c.y], x.y);
        atomicAdd(&out[c.z], x.z); atomicAdd(&out[c.w], x.w);
    }
    for (int i = (nvec << 2) + tid; i < nnz; i += stride)
        atomicAdd(&out[col_idx[i]], values[i]);
}

extern "C" void kernel_launch(void* const* d_in, const int* in_sizes, int n_in,
                              void* d_out, int out_size, void* d_ws, size_t ws_size,
                              hipStream_t stream) {
    const int*   col_idx = (const int*)d_in[1];
    const float* values  = (const float*)d_in[2];
    float*       out     = (float*)d_out;
    const int    nnz     = in_sizes[1];
    const int    ncols   = out_size;

    // pad each private copy to a 256 B multiple so no L2 line is shared
    // between two owning workgroups (non-coherent L2 writeback hazard)
    const int    copy_stride = (ncols + 63) & ~63;   // floats
    const size_t ws_needed   = (size_t)NB * copy_stride * sizeof(float);

    if (ws_size >= ws_needed) {
        float* ws = (float*)d_ws;
        // 1) zero the private copies (poisoned to 0xAA; accumulation needs 0)
        {
            int nvec4 = (NB * copy_stride) >> 2;   // copy_stride % 4 == 0
            zero_ws_kernel<<<2048, 256, 0, stream>>>((float4*)ws, nvec4);
        }
        // 2) scatter into per-workgroup copies with workgroup-scope atomics
        scatter_priv_kernel<<<NB, TPB, 0, stream>>>(col_idx, values, ws,
                                                    nnz, copy_stride);
        // 3) reduce the NB copies into d_out (overwrites every element)
        {
            int blocks = (ncols + 255) / 256;
            reduce_priv_kernel<<<blocks, 256, 0, stream>>>(ws, out, ncols,
                                                           copy_stride);
        }
    } else {
        // fallback: direct device-scope atomics
        int blocks = (ncols + 255) / 256;
        zero_out_kernel<<<blocks, 256, 0, stream>>>(out, ncols);
        scatter_add_kernel<<<2048, 256, 0, stream>>>(col_idx, values, out, nnz);
    }
}

// Round 3
// 120.714 us; speedup vs baseline: 8.4169x; 8.3640x over previous
//
#include <hip/hip_runtime.h>

// segment_sum: out[col_idx[i]] += values[i], out = float32[n_cols].
// Inputs: d_in[0]=row_idx (UNUSED), d_in[1]=col_idx (i32), d_in[2]=values (f32),
// d_in[3]=n_rows, d_in[4]=n_cols.
//
// Round-2 lesson: global f32 atomics on gfx950 write through 32B each at a
// hard ~20G atomics/s ceiling regardless of scope/contention (WRITE_SIZE
// 623MB invariant). So: accumulate in LDS only. Columns split into R=4
// ranges of RS=25088 (98KB LDS/block); grid = (B chunks) x (R ranges);
// each block filters its chunk to its range, ds_add_f32 into LDS, dumps
// the histogram to ws; a reduce kernel sums the B copies per range.

constexpr int R  = 4;       // column ranges (passes over the input)
constexpr int RS = 25088;   // columns per range; RS*4 = 100352 B LDS
constexpr int B  = 64;      // chunks per range -> B*R = 256 blocks = 1/CU
#define TPB 1024

__global__ __launch_bounds__(TPB)
void scatter_lds_kernel(const int* __restrict__ col_idx,
                        const float* __restrict__ values,
                        float* __restrict__ ws,
                        int nnz) {
    __shared__ float hist[RS];

    const int b    = blockIdx.x;          // chunk index
    const int r    = blockIdx.y;          // range index
    const int base = r * RS;

    for (int i = threadIdx.x; i < RS; i += TPB) hist[i] = 0.0f;
    __syncthreads();

    const int nvec = nnz >> 2;
    const int per  = (nvec + B - 1) / B;
    const int v0   = b * per;
    const int v1   = min(nvec, v0 + per);

    const int4*   c4 = reinterpret_cast<const int4*>(col_idx);
    const float4* v4 = reinterpret_cast<const float4*>(values);

    for (int v = v0 + threadIdx.x; v < v1; v += TPB) {
        int4   c = c4[v];
        float4 x = v4[v];
        unsigned d;
        d = (unsigned)(c.x - base); if (d < (unsigned)RS) atomicAdd(&hist[d], x.x);
        d = (unsigned)(c.y - base); if (d < (unsigned)RS) atomicAdd(&hist[d], x.y);
        d = (unsigned)(c.z - base); if (d < (unsigned)RS) atomicAdd(&hist[d], x.z);
        d = (unsigned)(c.w - base); if (d < (unsigned)RS) atomicAdd(&hist[d], x.w);
    }
    // tail elements (nnz % 4) handled by the last chunk's blocks
    if (b == B - 1) {
        for (int i = (nvec << 2) + threadIdx.x; i < nnz; i += TPB) {
            unsigned d = (unsigned)(col_idx[i] - base);
            if (d < (unsigned)RS) atomicAdd(&hist[d], values[i]);
        }
    }
    __syncthreads();

    // dump histogram (coalesced float4) to ws copy (r*B + b)
    float4* dst = reinterpret_cast<float4*>(ws + (size_t)(r * B + b) * RS);
    const float4* src = reinterpret_cast<const float4*>(hist);
    for (int i = threadIdx.x; i < (RS >> 2); i += TPB) dst[i] = src[i];
}

__global__ void reduce_kernel(const float* __restrict__ ws,
                              float* __restrict__ out,
                              int ncols) {
    int c = blockIdx.x * blockDim.x + threadIdx.x;
    if (c >= ncols) return;
    int r     = c / RS;
    int local = c - r * RS;
    const float* p = ws + (size_t)(r * B) * RS + local;
    float s = 0.0f;
#pragma unroll 8
    for (int b = 0; b < B; ++b) s += p[(size_t)b * RS];
    out[c] = s;
}

// ---- fallback (generality / tiny ws): direct device-scope atomics ----
__global__ void zero_out_kernel(float* __restrict__ out, int n) {
    int i = blockIdx.x * blockDim.x + threadIdx.x;
    if (i < n) out[i] = 0.0f;
}
__global__ void scatter_add_kernel(const int* __restrict__ col_idx,
                                   const float* __restrict__ values,
                                   float* __restrict__ out, int nnz) {
    const int tid    = blockIdx.x * blockDim.x + threadIdx.x;
    const int stride = gridDim.x * blockDim.x;
    const int nvec = nnz >> 2;
    const int4*   c4 = reinterpret_cast<const int4*>(col_idx);
    const float4* v4 = reinterpret_cast<const float4*>(values);
    for (int v = tid; v < nvec; v += stride) {
        int4 c = c4[v]; float4 x = v4[v];
        atomicAdd(&out[c.x], x.x); atomicAdd(&out[c.y], x.y);
        atomicAdd(&out[c.z], x.z); atomicAdd(&out[c.w], x.w);
    }
    for (int i = (nvec << 2) + tid; i < nnz; i += stride)
        atomicAdd(&out[col_idx[i]], values[i]);
}

extern "C" void kernel_launch(void* const* d_in, const int* in_sizes, int n_in,
                              void* d_out, int out_size, void* d_ws, size_t ws_size,
                              hipStream_t stream) {
    const int*   col_idx = (const int*)d_in[1];
    const float* values  = (const float*)d_in[2];
    float*       out     = (float*)d_out;
    const int    nnz     = in_sizes[1];
    const int    ncols   = out_size;

    const size_t ws_needed = (size_t)R * B * RS * sizeof(float);  // ~25.7 MB

    if (ncols <= R * RS && ws_size >= ws_needed) {
        float* ws = (float*)d_ws;
        dim3 grid(B, R);
        scatter_lds_kernel<<<grid, TPB, 0, stream>>>(col_idx, values, ws, nnz);
        int blocks = (ncols + 255) / 256;
        reduce_kernel<<<blocks, 256, 0, stream>>>(ws, out, ncols);
    } else {
        int blocks = (ncols + 255) / 256;
        zero_out_kernel<<<blocks, 256, 0, stream>>>(out, ncols);
        scatter_add_kernel<<<2048, 256, 0, stream>>>(col_idx, values, out, nnz);
    }
}